// Round 5
// baseline (385.546 us; speedup 1.0000x reference)
//
#include <hip/hip_runtime.h>

#define NCOL 90                 // 5*B + C = 10 + 80
#define LAMBDA_COORD 5.0f
#define LAMBDA_NOOBJ 0.5f
#define NBLOCKS 6272            // 200704 cells * 8 lanes / 256

// 8 lanes per cell, direct global loads, register-batched.
// Lane r: class float2s at cols 10+2r+16k (k=0..4) — exact cover of cols 10..89.
// Box cols 0..9 loaded by all 8 lanes (same cache lines, broadcast); box math
// predicated on r==0. __launch_bounds__(256,4): VGPR cap 128 so the compiler
// batches all loads before use (R2's VGPR=24 serialized them).
__global__ __launch_bounds__(256, 4) void yolo_kernel(
    const float* __restrict__ pred,
    const float* __restrict__ targ,
    float* __restrict__ partials,
    unsigned int* __restrict__ counter,
    float* __restrict__ out)
{
    const float inv_s = 1.0f / 7.0f;
    const int tid  = blockIdx.x * 256 + threadIdx.x;
    const int cell = tid >> 3;
    const int r    = tid & 7;
    const int lane = threadIdx.x & 63;
    const int wave = threadIdx.x >> 6;

    const float* pc = pred + (size_t)cell * NCOL;
    const float* tc = targ + (size_t)cell * NCOL;

    // ---- issue ALL loads first (batched into registers) ----
    float2 pcv[5], tcv[5];          // class data, this lane's share
#pragma unroll
    for (int k = 0; k < 5; ++k)
        pcv[k] = *reinterpret_cast<const float2*>(pc + 10 + 2 * r + 16 * k);
#pragma unroll
    for (int k = 0; k < 5; ++k)
        tcv[k] = *reinterpret_cast<const float2*>(tc + 10 + 2 * r + 16 * k);

    float2 pb[5], tb[5];            // box cols 0..9 (broadcast within group)
#pragma unroll
    for (int i = 0; i < 5; ++i)
        pb[i] = *reinterpret_cast<const float2*>(pc + 2 * i);
#pragma unroll
    for (int i = 0; i < 5; ++i)
        tb[i] = *reinterpret_cast<const float2*>(tc + 2 * i);

    // ---- class term ----
    float cls = 0.0f;
#pragma unroll
    for (int k = 0; k < 5; ++k) {
        float dx = pcv[k].x - tcv[k].x;
        float dy = pcv[k].y - tcv[k].y;
        cls += dx * dx + dy * dy;
    }

    float conf_t  = tb[2].x;        // targ col 4
    float coord_m = (conf_t > 0.0f) ? 1.0f : 0.0f;
    float loss = coord_m * cls;

    // ---- box term (1 lane per cell) ----
    if (r == 0) {
        float p[10] = { pb[0].x, pb[0].y, pb[1].x, pb[1].y, pb[2].x,
                        pb[2].y, pb[3].x, pb[3].y, pb[4].x, pb[4].y };
        float t[10] = { tb[0].x, tb[0].y, tb[1].x, tb[1].y, tb[2].x,
                        tb[2].y, tb[3].x, tb[3].y, tb[4].x, tb[4].y };

        float noobj_m = (conf_t == 0.0f) ? 1.0f : 0.0f;
        float d4 = p[4] - t[4];
        float d9 = p[9] - t[9];
        float noobj = noobj_m * (d4 * d4 + d9 * d9);

        float tax = t[0] * inv_s - 0.5f * t[2];
        float tay = t[1] * inv_s - 0.5f * t[3];
        float tbx = tax * inv_s + 0.5f * t[2];
        float tby = tay * inv_s + 0.5f * t[3];
        float t_area = (tbx - tax) * (tby - tay);

        float pax[2], pay[2], pbx[2], pby[2], iou[2];
#pragma unroll
        for (int b = 0; b < 2; ++b) {
            const float* q = p + 5 * b;
            float ax = q[0] * inv_s - 0.5f * q[2];
            float ay = q[1] * inv_s - 0.5f * q[3];
            float bx = ax * inv_s + 0.5f * q[2];
            float by = ay * inv_s + 0.5f * q[3];
            pax[b] = ax; pay[b] = ay; pbx[b] = bx; pby[b] = by;
            float tlx = fmaxf(ax, tax);
            float tly = fmaxf(ay, tay);
            float brx = fminf(bx, tbx);
            float bry = fminf(by, tby);
            float w = fmaxf(brx - tlx, 0.0f);
            float h = fmaxf(bry - tly, 0.0f);
            float inter = w * h;
            float parea = (bx - ax) * (by - ay);
            iou[b] = inter / (parea + t_area - inter);
        }

        int idx = (iou[1] > iou[0]) ? 1 : 0;   // argmax, first-max-on-tie
        float tiou = idx ? iou[1] : iou[0];

        float psx = idx ? pax[1] : pax[0];
        float psy = idx ? pay[1] : pay[0];
        float psw = idx ? pbx[1] : pbx[0];
        float psh = idx ? pby[1] : pby[0];
        float psc = idx ? p[9] : p[4];

        float tsx, tsy, tsw, tsh;
        if (idx == 0) { tsx = tax; tsy = tay; tsw = tbx; tsh = tby; }
        else          { tsx = t[5]; tsy = t[6]; tsw = t[7]; tsh = t[8]; }

        float dx = psx - tsx;
        float dy = psy - tsy;
        float dw = psw - tsw;
        float dh = psh - tsh;
        float xy = dx * dx + dy * dy;
        float wh = dw * dw + dh * dh;
        float dc = psc - tiou;

        loss += coord_m * (LAMBDA_COORD * (xy + wh) + dc * dc)
              + LAMBDA_NOOBJ * noobj;
    }

    // ---- wave + block reduce ----
#pragma unroll
    for (int off = 32; off > 0; off >>= 1)
        loss += __shfl_down(loss, off, 64);

    __shared__ float red[4];
    __shared__ int is_last;
    if (lane == 0) red[wave] = loss;
    __syncthreads();

    if (threadIdx.x == 0) {
        float val = red[0] + red[1] + red[2] + red[3];
        __hip_atomic_store(&partials[blockIdx.x], val,
                           __ATOMIC_RELAXED, __HIP_MEMORY_SCOPE_AGENT);
        __threadfence();
        unsigned int prev = __hip_atomic_fetch_add(counter, 1u,
                           __ATOMIC_ACQ_REL, __HIP_MEMORY_SCOPE_AGENT);
        is_last = (prev == NBLOCKS - 1) ? 1 : 0;
    }
    __syncthreads();

    if (is_last) {                  // last block sums the 6272 partials
        float s = 0.0f;
        for (int i = threadIdx.x; i < NBLOCKS; i += 256)
            s += __hip_atomic_load(&partials[i],
                                   __ATOMIC_RELAXED, __HIP_MEMORY_SCOPE_AGENT);
#pragma unroll
        for (int off = 32; off > 0; off >>= 1)
            s += __shfl_down(s, off, 64);
        if (lane == 0) red[wave] = s;
        __syncthreads();
        if (threadIdx.x == 0)
            out[0] = (red[0] + red[1] + red[2] + red[3]) * (1.0f / 4096.0f);
    }
}

extern "C" void kernel_launch(void* const* d_in, const int* in_sizes, int n_in,
                              void* d_out, int out_size, void* d_ws, size_t ws_size,
                              hipStream_t stream) {
    const float* pred = (const float*)d_in[0];
    const float* targ = (const float*)d_in[1];
    float* out = (float*)d_out;

    float* partials       = (float*)d_ws;                         // 6272 floats
    unsigned int* counter = (unsigned int*)((char*)d_ws + NBLOCKS * 4);

    hipMemsetAsync(counter, 0, sizeof(unsigned int), stream);
    yolo_kernel<<<NBLOCKS, 256, 0, stream>>>(pred, targ, partials, counter, out);
}

// Round 6
// 33.963 us; speedup vs baseline: 11.3519x; 11.3519x over previous
//
#include <hip/hip_runtime.h>

#define NCOL 90                       // 5*B + C = 10 + 80
#define CB 32                         // cells per block
#define CHUNKF (CB * NCOL)            // 2880 floats per array (11520 B)
#define LAMBDA_COORD 5.0f
#define LAMBDA_NOOBJ 0.5f

typedef const __attribute__((address_space(1))) void* gas_ptr;
typedef __attribute__((address_space(3))) void* las_ptr;

__device__ __forceinline__ void dma16(const float* g, float* l) {
    __builtin_amdgcn_global_load_lds((gas_ptr)g, (las_ptr)l, 16, 0, 0);
}
__device__ __forceinline__ void dma4(const float* g, float* l) {
    __builtin_amdgcn_global_load_lds((gas_ptr)g, (las_ptr)l, 4, 0, 0);
}

// One-shot block: stage 32 cells of pred+targ (23040 B) into LDS via DMA
// (24 ops, 6 per wave), drain, compute 8 lanes/cell, block-reduce, store
// one partial. 23 KB LDS -> 6 resident blocks/CU (75% wave occupancy):
// cross-block phase stagger hides each block's drain latency.
__global__ __launch_bounds__(256) void yolo_cell_kernel(
    const float* __restrict__ pred,
    const float* __restrict__ targ,
    float* __restrict__ partials)
{
    __shared__ float lds[2 * CHUNKF];         // 23040 B
    __shared__ float red[4];

    const float inv_s = 1.0f / 7.0f;
    const int wave = threadIdx.x >> 6;
    const int lane = threadIdx.x & 63;

    const float* psrc = pred + (size_t)blockIdx.x * CHUNKF;
    const float* tsrc = targ + (size_t)blockIdx.x * CHUNKF;

    // 24 DMA ops: per array 11x dma16 (1KB each) + 1x dma4 (256B tail).
    // Wave w issues ops o = w + 4m -> exactly 6 per wave.
#pragma unroll
    for (int m = 0; m < 6; ++m) {
        int o = wave + 4 * m;                 // 0..23
        int a = (o >= 12) ? 1 : 0;            // 0=pred, 1=targ
        int j = o - a * 12;                   // 0..11
        const float* s = a ? tsrc : psrc;
        float* d = lds + (a ? CHUNKF : 0);
        if (j < 11) dma16(s + j * 256 + lane * 4, d + j * 256);
        else        dma4 (s + 2816 + lane,        d + 2816);
    }
    asm volatile("s_waitcnt vmcnt(0)" ::: "memory");
    __syncthreads();

    // ---- compute: 8 lanes per cell, from LDS ----
    const int g = threadIdx.x >> 3;           // cell 0..31
    const int r = threadIdx.x & 7;
    const float* lp = lds + g * NCOL;
    const float* lt = lds + CHUNKF + g * NCOL;

    // class sweep: lane r covers float2s at cols 2r+16k with col>=10
    float cls_acc = 0.0f;
#pragma unroll
    for (int k = 0; k < 6; ++k) {
        int col = 2 * r + 16 * k;
        if (col >= 10 && col < NCOL) {        // pairs never straddle boundary
            float2 a = *reinterpret_cast<const float2*>(lp + col);
            float2 b = *reinterpret_cast<const float2*>(lt + col);
            float dx = a.x - b.x;
            float dy = a.y - b.y;
            cls_acc += dx * dx + dy * dy;
        }
    }

    float conf_t  = lt[4];
    float coord_m = (conf_t > 0.0f) ? 1.0f : 0.0f;
    float loss = coord_m * cls_acc;

    if (r == 0) {                             // box math: 1 lane per cell
        float p[10], t[10];
#pragma unroll
        for (int i = 0; i < 10; ++i) { p[i] = lp[i]; t[i] = lt[i]; }

        float noobj_m = (conf_t == 0.0f) ? 1.0f : 0.0f;
        float d4 = p[4] - t[4];
        float d9 = p[9] - t[9];
        float noobj = noobj_m * (d4 * d4 + d9 * d9);

        float tax = t[0] * inv_s - 0.5f * t[2];
        float tay = t[1] * inv_s - 0.5f * t[3];
        float tbx = tax * inv_s + 0.5f * t[2];
        float tby = tay * inv_s + 0.5f * t[3];
        float t_area = (tbx - tax) * (tby - tay);

        float pax[2], pay[2], pbx[2], pby[2], iou[2];
#pragma unroll
        for (int b = 0; b < 2; ++b) {
            const float* q = p + 5 * b;
            float ax = q[0] * inv_s - 0.5f * q[2];
            float ay = q[1] * inv_s - 0.5f * q[3];
            float bx = ax * inv_s + 0.5f * q[2];
            float by = ay * inv_s + 0.5f * q[3];
            pax[b] = ax; pay[b] = ay; pbx[b] = bx; pby[b] = by;
            float tlx = fmaxf(ax, tax);
            float tly = fmaxf(ay, tay);
            float brx = fminf(bx, tbx);
            float bry = fminf(by, tby);
            float w = fmaxf(brx - tlx, 0.0f);
            float h = fmaxf(bry - tly, 0.0f);
            float inter = w * h;
            float parea = (bx - ax) * (by - ay);
            iou[b] = inter / (parea + t_area - inter);
        }

        int idx = (iou[1] > iou[0]) ? 1 : 0;  // argmax, first-max-on-tie
        float tiou = idx ? iou[1] : iou[0];

        float psx = idx ? pax[1] : pax[0];
        float psy = idx ? pay[1] : pay[0];
        float psw = idx ? pbx[1] : pbx[0];
        float psh = idx ? pby[1] : pby[0];
        float psc = idx ? p[9] : p[4];

        float tsx, tsy, tsw, tsh;             // transformed first box or RAW 2nd
        if (idx == 0) { tsx = tax; tsy = tay; tsw = tbx; tsh = tby; }
        else          { tsx = t[5]; tsy = t[6]; tsw = t[7]; tsh = t[8]; }

        float dx = psx - tsx;
        float dy = psy - tsy;
        float dw = psw - tsw;
        float dh = psh - tsh;
        float xy = dx * dx + dy * dy;
        float wh = dw * dw + dh * dh;
        float dc = psc - tiou;

        loss += coord_m * (LAMBDA_COORD * (xy + wh) + dc * dc)
              + LAMBDA_NOOBJ * noobj;
    }

    // wave + block reduce, plain partial store (no atomics — R5 lesson)
#pragma unroll
    for (int off = 32; off > 0; off >>= 1)
        loss += __shfl_down(loss, off, 64);
    if (lane == 0) red[wave] = loss;
    __syncthreads();
    if (threadIdx.x == 0)
        partials[blockIdx.x] = red[0] + red[1] + red[2] + red[3];
}

__global__ __launch_bounds__(256) void yolo_reduce_kernel(
    const float* __restrict__ partials, int n, float* __restrict__ out)
{
    float s = 0.0f;
    for (int i = threadIdx.x; i < n; i += blockDim.x)
        s += partials[i];
#pragma unroll
    for (int off = 32; off > 0; off >>= 1)
        s += __shfl_down(s, off, 64);

    __shared__ float red[4];
    int lane = threadIdx.x & 63;
    int wid  = threadIdx.x >> 6;
    if (lane == 0) red[wid] = s;
    __syncthreads();
    if (threadIdx.x == 0)
        out[0] = (red[0] + red[1] + red[2] + red[3]) * (1.0f / 4096.0f);
}

extern "C" void kernel_launch(void* const* d_in, const int* in_sizes, int n_in,
                              void* d_out, int out_size, void* d_ws, size_t ws_size,
                              hipStream_t stream) {
    const float* pred = (const float*)d_in[0];
    const float* targ = (const float*)d_in[1];
    float* out = (float*)d_out;

    int ncells  = in_sizes[0] / NCOL;         // 200704
    int nblocks = ncells / CB;                // 6272 (exact)

    float* partials = (float*)d_ws;           // 6272 floats scratch

    yolo_cell_kernel<<<nblocks, 256, 0, stream>>>(pred, targ, partials);
    yolo_reduce_kernel<<<1, 256, 0, stream>>>(partials, nblocks, out);
}

// Round 7
// 27.323 us; speedup vs baseline: 14.1109x; 1.2430x over previous
//
#include <hip/hip_runtime.h>

#define NCOL 90                 // 5*B + C = 10 + 80
#define LAMBDA_COORD 5.0f
#define LAMBDA_NOOBJ 0.5f

// 8 lanes per cell, direct loads, data-dependent skip:
//  - every lane reads targ[4] (same addr within the 8-lane group -> 1 request)
//  - t4 == 0 (75% of cells): only the noobj term -> 3 extra scalar loads on r==0
//  - t4 > 0  (25%): full class sweep (lane r: float2s at cols 10+2r+16k,
//    exact cover of 10..89, 64 B-coalesced per group) + box math on r==0.
// This cuts bytes/cell from 720 to ~290 avg; the multiplied-by-zero terms in
// the reference are skipped, arithmetic is otherwise identical.
__global__ __launch_bounds__(256) void yolo_cell_kernel(
    const float* __restrict__ pred,
    const float* __restrict__ targ,
    float* __restrict__ partials,
    int ncells)
{
    const float inv_s = 1.0f / 7.0f;
    const int tid  = blockIdx.x * 256 + threadIdx.x;
    const int cell = tid >> 3;
    const int r    = tid & 7;
    const int lane = threadIdx.x & 63;
    const int wave = threadIdx.x >> 6;

    float loss = 0.0f;
    if (cell < ncells) {
        const float* pc = pred + (size_t)cell * NCOL;
        const float* tc = targ + (size_t)cell * NCOL;

        float t4 = tc[4];               // group-uniform broadcast load

        if (t4 == 0.0f) {
            if (r == 0) {               // noobj confidence term only
                float t9 = tc[9];
                float p4 = pc[4];
                float p9 = pc[9];
                float d4 = p4 - t4;
                float d9 = p9 - t9;
                loss = LAMBDA_NOOBJ * (d4 * d4 + d9 * d9);
            }
        } else if (t4 > 0.0f) {         // coord_m == 1 cell
            // ---- class term: batched coalesced loads ----
            float2 pcv[5], tcv[5];
#pragma unroll
            for (int k = 0; k < 5; ++k)
                pcv[k] = *reinterpret_cast<const float2*>(pc + 10 + 2 * r + 16 * k);
#pragma unroll
            for (int k = 0; k < 5; ++k)
                tcv[k] = *reinterpret_cast<const float2*>(tc + 10 + 2 * r + 16 * k);

            float cls = 0.0f;
#pragma unroll
            for (int k = 0; k < 5; ++k) {
                float dx = pcv[k].x - tcv[k].x;
                float dy = pcv[k].y - tcv[k].y;
                cls += dx * dx + dy * dy;
            }
            loss = cls;

            if (r == 0) {               // box + conf math, 1 lane per cell
                float p[10], t[10];
#pragma unroll
                for (int i = 0; i < 5; ++i) {
                    float2 a = *reinterpret_cast<const float2*>(pc + 2 * i);
                    float2 b = *reinterpret_cast<const float2*>(tc + 2 * i);
                    p[2*i] = a.x; p[2*i+1] = a.y;
                    t[2*i] = b.x; t[2*i+1] = b.y;
                }

                float tax = t[0] * inv_s - 0.5f * t[2];
                float tay = t[1] * inv_s - 0.5f * t[3];
                float tbx = tax * inv_s + 0.5f * t[2];
                float tby = tay * inv_s + 0.5f * t[3];
                float t_area = (tbx - tax) * (tby - tay);

                float pax[2], pay[2], pbx[2], pby[2], iou[2];
#pragma unroll
                for (int b = 0; b < 2; ++b) {
                    const float* q = p + 5 * b;
                    float ax = q[0] * inv_s - 0.5f * q[2];
                    float ay = q[1] * inv_s - 0.5f * q[3];
                    float bx = ax * inv_s + 0.5f * q[2];
                    float by = ay * inv_s + 0.5f * q[3];
                    pax[b] = ax; pay[b] = ay; pbx[b] = bx; pby[b] = by;
                    float tlx = fmaxf(ax, tax);
                    float tly = fmaxf(ay, tay);
                    float brx = fminf(bx, tbx);
                    float bry = fminf(by, tby);
                    float w = fmaxf(brx - tlx, 0.0f);
                    float h = fmaxf(bry - tly, 0.0f);
                    float inter = w * h;
                    float parea = (bx - ax) * (by - ay);
                    iou[b] = inter / (parea + t_area - inter);
                }

                int idx = (iou[1] > iou[0]) ? 1 : 0;   // first-max-on-tie
                float tiou = idx ? iou[1] : iou[0];

                float psx = idx ? pax[1] : pax[0];
                float psy = idx ? pay[1] : pay[0];
                float psw = idx ? pbx[1] : pbx[0];
                float psh = idx ? pby[1] : pby[0];
                float psc = idx ? p[9] : p[4];

                float tsx, tsy, tsw, tsh;   // transformed 1st box or RAW 2nd
                if (idx == 0) { tsx = tax; tsy = tay; tsw = tbx; tsh = tby; }
                else          { tsx = t[5]; tsy = t[6]; tsw = t[7]; tsh = t[8]; }

                float dx = psx - tsx;
                float dy = psy - tsy;
                float dw = psw - tsw;
                float dh = psh - tsh;
                float xy = dx * dx + dy * dy;
                float wh = dw * dw + dh * dh;
                float dc = psc - tiou;

                loss += LAMBDA_COORD * (xy + wh) + dc * dc;
            }
        }
        // t4 < 0: both masks are 0 in the reference -> contributes nothing
    }

    // ---- wave + block reduce, plain partial store ----
#pragma unroll
    for (int off = 32; off > 0; off >>= 1)
        loss += __shfl_down(loss, off, 64);

    __shared__ float red[4];
    if (lane == 0) red[wave] = loss;
    __syncthreads();
    if (threadIdx.x == 0)
        partials[blockIdx.x] = red[0] + red[1] + red[2] + red[3];
}

__global__ __launch_bounds__(256) void yolo_reduce_kernel(
    const float* __restrict__ partials, int n, float* __restrict__ out)
{
    float s = 0.0f;
    for (int i = threadIdx.x; i < n; i += blockDim.x)
        s += partials[i];
#pragma unroll
    for (int off = 32; off > 0; off >>= 1)
        s += __shfl_down(s, off, 64);

    __shared__ float red[4];
    int lane = threadIdx.x & 63;
    int wid  = threadIdx.x >> 6;
    if (lane == 0) red[wid] = s;
    __syncthreads();
    if (threadIdx.x == 0)
        out[0] = (red[0] + red[1] + red[2] + red[3]) * (1.0f / 4096.0f);
}

extern "C" void kernel_launch(void* const* d_in, const int* in_sizes, int n_in,
                              void* d_out, int out_size, void* d_ws, size_t ws_size,
                              hipStream_t stream) {
    const float* pred = (const float*)d_in[0];
    const float* targ = (const float*)d_in[1];
    float* out = (float*)d_out;

    int ncells   = in_sizes[0] / NCOL;               // 200704
    int nthreads = ncells * 8;
    int nblocks  = (nthreads + 255) / 256;           // 6272

    float* partials = (float*)d_ws;                  // 6272 floats scratch

    yolo_cell_kernel<<<nblocks, 256, 0, stream>>>(pred, targ, partials, ncells);
    yolo_reduce_kernel<<<1, 256, 0, stream>>>(partials, nblocks, out);
}

// Round 8
// 25.313 us; speedup vs baseline: 15.2311x; 1.0794x over previous
//
#include <hip/hip_runtime.h>

#define NCOL 90                 // 5*B + C = 10 + 80
#define LAMBDA_COORD 5.0f
#define LAMBDA_NOOBJ 0.5f

// 1 lane per cell probe + wave compaction:
//  - each lane probes its cell's targ[4] (+ targ[9], pred[4], pred[9] as
//    independent loads -> noobj term at full 64-lane density, one round-trip)
//  - obj cells (~25%) ballot-compacted into a per-wave LDS queue, then
//    processed in wave-uniform rounds: 8 cells x 8 lanes per round
//    (class sweep cols 10+2r+16k, exact cover of 10..89; box math on r==0).
// Same bytes as R7 (~60 MB), ~3x fewer load instructions, no dependent
// probe->noobj chain, near-full lane utilization on the obj path.
__global__ __launch_bounds__(256) void yolo_cell_kernel(
    const float* __restrict__ pred,
    const float* __restrict__ targ,
    float* __restrict__ partials)
{
    __shared__ int q[256];                 // 4 waves x 64-entry queue
    __shared__ float red[4];

    const float inv_s = 1.0f / 7.0f;
    const int lane = threadIdx.x & 63;
    const int wave = threadIdx.x >> 6;
    const int cell = blockIdx.x * 256 + threadIdx.x;   // grid is exact

    const float* pc = pred + (size_t)cell * NCOL;
    const float* tc = targ + (size_t)cell * NCOL;

    // ---- independent probes (batched, single round-trip) ----
    float t4 = tc[4];
    float t9 = tc[9];
    float p4 = pc[4];
    float p9 = pc[9];

    float loss = 0.0f;
    if (t4 == 0.0f) {                      // noobj term, full density
        float d4 = p4 - t4;
        float d9 = p9 - t9;
        loss = LAMBDA_NOOBJ * (d4 * d4 + d9 * d9);
    }

    // ---- compact obj cells into per-wave queue ----
    bool obj = (t4 > 0.0f);
    unsigned long long m = __ballot(obj);
    int n = __popcll(m);
    if (obj) {
        int pos = __popcll(m & ((1ull << lane) - 1ull));
        q[wave * 64 + pos] = cell;
    }
    // same-wave LDS ops are in-order; pin program order for the compiler
    __builtin_amdgcn_sched_barrier(0);

    // ---- obj rounds: 8 cells x 8 lanes, wave-uniform trip count ----
    const int g = lane >> 3;               // group 0..7 (cell slot)
    const int r = lane & 7;                // lane within group
    for (int j = 0; j * 8 < n; ++j) {
        int qi = j * 8 + g;
        bool valid = (qi < n);
        int oc = q[wave * 64 + (valid ? qi : 0)];
        const float* opc = pred + (size_t)oc * NCOL;
        const float* otc = targ + (size_t)oc * NCOL;

        if (valid) {
            // class term: lane r covers float2s at cols 10+2r+16k
            float2 pcv[5], tcv[5];
#pragma unroll
            for (int k = 0; k < 5; ++k)
                pcv[k] = *reinterpret_cast<const float2*>(opc + 10 + 2 * r + 16 * k);
#pragma unroll
            for (int k = 0; k < 5; ++k)
                tcv[k] = *reinterpret_cast<const float2*>(otc + 10 + 2 * r + 16 * k);

            float cls = 0.0f;
#pragma unroll
            for (int k = 0; k < 5; ++k) {
                float dx = pcv[k].x - tcv[k].x;
                float dy = pcv[k].y - tcv[k].y;
                cls += dx * dx + dy * dy;
            }
            loss += cls;

            if (r == 0) {                  // box + conf math, 1 lane per cell
                float p[10], t[10];
#pragma unroll
                for (int i = 0; i < 5; ++i) {
                    float2 a = *reinterpret_cast<const float2*>(opc + 2 * i);
                    float2 b = *reinterpret_cast<const float2*>(otc + 2 * i);
                    p[2*i] = a.x; p[2*i+1] = a.y;
                    t[2*i] = b.x; t[2*i+1] = b.y;
                }

                float tax = t[0] * inv_s - 0.5f * t[2];
                float tay = t[1] * inv_s - 0.5f * t[3];
                float tbx = tax * inv_s + 0.5f * t[2];
                float tby = tay * inv_s + 0.5f * t[3];
                float t_area = (tbx - tax) * (tby - tay);

                float pax[2], pay[2], pbx[2], pby[2], iou[2];
#pragma unroll
                for (int b = 0; b < 2; ++b) {
                    const float* qq = p + 5 * b;
                    float ax = qq[0] * inv_s - 0.5f * qq[2];
                    float ay = qq[1] * inv_s - 0.5f * qq[3];
                    float bx = ax * inv_s + 0.5f * qq[2];
                    float by = ay * inv_s + 0.5f * qq[3];
                    pax[b] = ax; pay[b] = ay; pbx[b] = bx; pby[b] = by;
                    float tlx = fmaxf(ax, tax);
                    float tly = fmaxf(ay, tay);
                    float brx = fminf(bx, tbx);
                    float bry = fminf(by, tby);
                    float w = fmaxf(brx - tlx, 0.0f);
                    float h = fmaxf(bry - tly, 0.0f);
                    float inter = w * h;
                    float parea = (bx - ax) * (by - ay);
                    iou[b] = inter / (parea + t_area - inter);
                }

                int idx = (iou[1] > iou[0]) ? 1 : 0;   // first-max-on-tie
                float tiou = idx ? iou[1] : iou[0];

                float psx = idx ? pax[1] : pax[0];
                float psy = idx ? pay[1] : pay[0];
                float psw = idx ? pbx[1] : pbx[0];
                float psh = idx ? pby[1] : pby[0];
                float psc = idx ? p[9] : p[4];

                float tsx, tsy, tsw, tsh;   // transformed 1st box or RAW 2nd
                if (idx == 0) { tsx = tax; tsy = tay; tsw = tbx; tsh = tby; }
                else          { tsx = t[5]; tsy = t[6]; tsw = t[7]; tsh = t[8]; }

                float dx = psx - tsx;
                float dy = psy - tsy;
                float dw = psw - tsw;
                float dh = psh - tsh;
                float xy = dx * dx + dy * dy;
                float wh = dw * dw + dh * dh;
                float dc = psc - tiou;

                loss += LAMBDA_COORD * (xy + wh) + dc * dc;
            }
        }
    }

    // ---- wave + block reduce, plain partial store ----
#pragma unroll
    for (int off = 32; off > 0; off >>= 1)
        loss += __shfl_down(loss, off, 64);
    if (lane == 0) red[wave] = loss;
    __syncthreads();
    if (threadIdx.x == 0)
        partials[blockIdx.x] = red[0] + red[1] + red[2] + red[3];
}

__global__ __launch_bounds__(256) void yolo_reduce_kernel(
    const float* __restrict__ partials, int n, float* __restrict__ out)
{
    float s = 0.0f;
    for (int i = threadIdx.x; i < n; i += blockDim.x)
        s += partials[i];
#pragma unroll
    for (int off = 32; off > 0; off >>= 1)
        s += __shfl_down(s, off, 64);

    __shared__ float red[4];
    int lane = threadIdx.x & 63;
    int wid  = threadIdx.x >> 6;
    if (lane == 0) red[wid] = s;
    __syncthreads();
    if (threadIdx.x == 0)
        out[0] = (red[0] + red[1] + red[2] + red[3]) * (1.0f / 4096.0f);
}

extern "C" void kernel_launch(void* const* d_in, const int* in_sizes, int n_in,
                              void* d_out, int out_size, void* d_ws, size_t ws_size,
                              hipStream_t stream) {
    const float* pred = (const float*)d_in[0];
    const float* targ = (const float*)d_in[1];
    float* out = (float*)d_out;

    int ncells  = in_sizes[0] / NCOL;        // 200704
    int nblocks = ncells / 256;              // 784 (exact)

    float* partials = (float*)d_ws;          // 784 floats scratch

    yolo_cell_kernel<<<nblocks, 256, 0, stream>>>(pred, targ, partials);
    yolo_reduce_kernel<<<1, 256, 0, stream>>>(partials, nblocks, out);
}

// Round 9
// 23.791 us; speedup vs baseline: 16.2057x; 1.0640x over previous
//
#include <hip/hip_runtime.h>

#define NCOL 90                 // 5*B + C = 10 + 80
#define LAMBDA_COORD 5.0f
#define LAMBDA_NOOBJ 0.5f

// 2 lanes per cell probe + wave compaction (R8 with 2x the waves):
//  - pair-split probe: even lane loads targ[4],targ[9], odd lane pred[4],pred[9]
//    of the SAME cell; one shfl_xor(1) exchange -> noobj term on even lanes.
//  - obj cells (~25% of the wave's 32 cells) ballot-compacted into a per-wave
//    queue; processed in wave-uniform rounds of 8 cells x 8 lanes
//    (class sweep cols 10+2r+16k = exact cover of 10..89; box math on r==0).
//  - 6272 waves (24.5/CU) vs R8's 3136: double TLP, half the rounds per wave.
__global__ __launch_bounds__(256, 6) void yolo_cell_kernel(
    const float* __restrict__ pred,
    const float* __restrict__ targ,
    float* __restrict__ partials)
{
    __shared__ int q[4][32];               // per-wave obj queue
    __shared__ float red[4];

    const float inv_s = 1.0f / 7.0f;
    const int lane = threadIdx.x & 63;
    const int wave = threadIdx.x >> 6;
    const int tid  = blockIdx.x * 256 + threadIdx.x;
    const int cell = tid >> 1;             // 2 lanes per cell (grid exact)
    const bool is_even = (lane & 1) == 0;

    const float* pc = pred + (size_t)cell * NCOL;
    const float* tc = targ + (size_t)cell * NCOL;

    // ---- pair-split probe, one round-trip ----
    const float* src = is_even ? tc : pc;
    float a = src[4];
    float b = src[9];
    float oa = __shfl_xor(a, 1, 64);       // even gets pred[4], odd gets targ[4]
    float ob = __shfl_xor(b, 1, 64);       // even gets pred[9], odd gets targ[9]

    float loss = 0.0f;
    bool obj = false;
    if (is_even) {                         // even lane owns the cell's probe math
        float t4 = a;
        if (t4 == 0.0f) {                  // noobj confidence term
            float d4 = oa - a;             // pred[4] - targ[4]
            float d9 = ob - b;             // pred[9] - targ[9]
            loss = LAMBDA_NOOBJ * (d4 * d4 + d9 * d9);
        }
        obj = (t4 > 0.0f);
    }

    // ---- compact obj cells into per-wave queue ----
    unsigned long long m = __ballot(obj);
    int n = __popcll(m);
    if (obj) {
        int pos = __popcll(m & ((1ull << lane) - 1ull));
        q[wave][pos] = cell;
    }
    __builtin_amdgcn_sched_barrier(0);     // pin write->read order in program

    // ---- obj rounds: 8 cells x 8 lanes, wave-uniform trip count ----
    const int g = lane >> 3;               // cell slot 0..7
    const int r = lane & 7;                // lane within cell group

    auto do_round = [&](int j) {
        int qi = j * 8 + g;
        bool valid = (qi < n);
        int oc = q[wave][valid ? qi : 0];
        const float* opc = pred + (size_t)oc * NCOL;
        const float* otc = targ + (size_t)oc * NCOL;

        if (valid) {
            // class term: lane r covers float2s at cols 10+2r+16k
            float2 pcv[5], tcv[5];
#pragma unroll
            for (int k = 0; k < 5; ++k)
                pcv[k] = *reinterpret_cast<const float2*>(opc + 10 + 2 * r + 16 * k);
#pragma unroll
            for (int k = 0; k < 5; ++k)
                tcv[k] = *reinterpret_cast<const float2*>(otc + 10 + 2 * r + 16 * k);

            float cls = 0.0f;
#pragma unroll
            for (int k = 0; k < 5; ++k) {
                float dx = pcv[k].x - tcv[k].x;
                float dy = pcv[k].y - tcv[k].y;
                cls += dx * dx + dy * dy;
            }
            loss += cls;

            if (r == 0) {                  // box + conf math, 1 lane per cell
                float p[10], t[10];
#pragma unroll
                for (int i = 0; i < 5; ++i) {
                    float2 av = *reinterpret_cast<const float2*>(opc + 2 * i);
                    float2 bv = *reinterpret_cast<const float2*>(otc + 2 * i);
                    p[2*i] = av.x; p[2*i+1] = av.y;
                    t[2*i] = bv.x; t[2*i+1] = bv.y;
                }

                float tax = t[0] * inv_s - 0.5f * t[2];
                float tay = t[1] * inv_s - 0.5f * t[3];
                float tbx = tax * inv_s + 0.5f * t[2];
                float tby = tay * inv_s + 0.5f * t[3];
                float t_area = (tbx - tax) * (tby - tay);

                float pax[2], pay[2], pbx[2], pby[2], iou[2];
#pragma unroll
                for (int bb = 0; bb < 2; ++bb) {
                    const float* qq = p + 5 * bb;
                    float ax = qq[0] * inv_s - 0.5f * qq[2];
                    float ay = qq[1] * inv_s - 0.5f * qq[3];
                    float bx = ax * inv_s + 0.5f * qq[2];
                    float by = ay * inv_s + 0.5f * qq[3];
                    pax[bb] = ax; pay[bb] = ay; pbx[bb] = bx; pby[bb] = by;
                    float tlx = fmaxf(ax, tax);
                    float tly = fmaxf(ay, tay);
                    float brx = fminf(bx, tbx);
                    float bry = fminf(by, tby);
                    float w = fmaxf(brx - tlx, 0.0f);
                    float h = fmaxf(bry - tly, 0.0f);
                    float inter = w * h;
                    float parea = (bx - ax) * (by - ay);
                    iou[bb] = inter / (parea + t_area - inter);
                }

                int idx = (iou[1] > iou[0]) ? 1 : 0;   // first-max-on-tie
                float tiou = idx ? iou[1] : iou[0];

                float psx = idx ? pax[1] : pax[0];
                float psy = idx ? pay[1] : pay[0];
                float psw = idx ? pbx[1] : pbx[0];
                float psh = idx ? pby[1] : pby[0];
                float psc = idx ? p[9] : p[4];

                float tsx, tsy, tsw, tsh;   // transformed 1st box or RAW 2nd
                if (idx == 0) { tsx = tax; tsy = tay; tsw = tbx; tsh = tby; }
                else          { tsx = t[5]; tsy = t[6]; tsw = t[7]; tsh = t[8]; }

                float dx = psx - tsx;
                float dy = psy - tsy;
                float dw = psw - tsw;
                float dh = psh - tsh;
                float xy = dx * dx + dy * dy;
                float wh = dw * dw + dh * dh;
                float dc = psc - tiou;

                loss += LAMBDA_COORD * (xy + wh) + dc * dc;
            }
        }
    };

    if (n > 0) do_round(0);
    if (n > 8) do_round(1);
    for (int j = 2; j * 8 < n; ++j) do_round(j);   // rare tail (n>16)

    // ---- wave + block reduce, plain partial store ----
#pragma unroll
    for (int off = 32; off > 0; off >>= 1)
        loss += __shfl_down(loss, off, 64);
    if (lane == 0) red[wave] = loss;
    __syncthreads();
    if (threadIdx.x == 0)
        partials[blockIdx.x] = red[0] + red[1] + red[2] + red[3];
}

__global__ __launch_bounds__(256) void yolo_reduce_kernel(
    const float* __restrict__ partials, int n, float* __restrict__ out)
{
    float s = 0.0f;
    for (int i = threadIdx.x; i < n; i += blockDim.x)
        s += partials[i];
#pragma unroll
    for (int off = 32; off > 0; off >>= 1)
        s += __shfl_down(s, off, 64);

    __shared__ float red[4];
    int lane = threadIdx.x & 63;
    int wid  = threadIdx.x >> 6;
    if (lane == 0) red[wid] = s;
    __syncthreads();
    if (threadIdx.x == 0)
        out[0] = (red[0] + red[1] + red[2] + red[3]) * (1.0f / 4096.0f);
}

extern "C" void kernel_launch(void* const* d_in, const int* in_sizes, int n_in,
                              void* d_out, int out_size, void* d_ws, size_t ws_size,
                              hipStream_t stream) {
    const float* pred = (const float*)d_in[0];
    const float* targ = (const float*)d_in[1];
    float* out = (float*)d_out;

    int ncells  = in_sizes[0] / NCOL;        // 200704
    int nblocks = ncells * 2 / 256;          // 1568 (exact)

    float* partials = (float*)d_ws;          // 1568 floats scratch

    yolo_cell_kernel<<<nblocks, 256, 0, stream>>>(pred, targ, partials);
    yolo_reduce_kernel<<<1, 256, 0, stream>>>(partials, nblocks, out);
}